// Round 9
// baseline (7532.628 us; speedup 1.0000x reference)
//
#include <hip/hip_runtime.h>
#include <hip/hip_bf16.h>
#include <math.h>

#define TS   256
#define CTS  512
#define MB   64
#define D    512
#define KMIX 20

// d_out layout (floats): hiddens [TS][MB][D], att_k [TS][MB][KMIX], att_w [TS][MB][D]
#define HID_SIZE  (TS*MB*D)
#define ATTK_OFF  (HID_SIZE)
#define ATTW_OFF  (HID_SIZE + TS*MB*KMIX)

// ws layout (bytes):
#define WS_WRPK  0
#define WS_UPK   524288
#define WS_ALPHA 1048576
#define WS_BETA  2359296
#define WS_KINC  3670016
#define WS_X     5242880
#define WS_F2    38797312

typedef __attribute__((ext_vector_type(8))) short bf16x8;
typedef __attribute__((ext_vector_type(4))) float f32x4;

__device__ __forceinline__ unsigned short f2bf(float v) {
  __hip_bfloat16 h = __float2bfloat16(v);
  union { __hip_bfloat16 h; unsigned short u; } cvt; cvt.h = h;
  return cvt.u;
}

// ---------------- K0: pack recurrence weights into MFMA B-fragment order ----------------
// Fragment f = nt*16 + kt. Element (f, lane l, e): k = kt*32 + (l>>4)*8 + e ; n = nt*16 + (l&15).
__global__ __launch_bounds__(256) void pack_weights(const float* __restrict__ Wur,
                                                    const float* __restrict__ U,
                                                    unsigned short* __restrict__ WrPK,
                                                    unsigned short* __restrict__ UPK) {
  int idx = blockIdx.x * 256 + threadIdx.x;    // 512*512 = 262144 total
  int l = idx & 63;
  int e = (idx >> 6) & 7;
  int f = idx >> 9;
  int kt = f & 15, nt = f >> 4;
  int k = kt * 32 + ((l >> 4) << 3) + e;
  int n = (nt << 4) + (l & 15);
  int o = ((f * 64 + l) << 3) + e;
  WrPK[o] = f2bf(Wur[k * 1024 + 512 + n]);
  UPK[o]  = f2bf(U[k * 512 + n]);
}

// ---------------- K1: alpha = inp@Wa+ba (log domain), beta, kinc ----------------
#define ABK_ROWS 8
__global__ __launch_bounds__(64) void abk_kernel(const float* __restrict__ inp,
                                                 const float* __restrict__ Wa, const float* __restrict__ ba,
                                                 const float* __restrict__ Wb, const float* __restrict__ bb_,
                                                 const float* __restrict__ Wk, const float* __restrict__ bk,
                                                 float* __restrict__ alpha, float* __restrict__ beta,
                                                 float* __restrict__ kinc) {
  __shared__ float rows[ABK_ROWS][D];
  int tb0 = blockIdx.x * ABK_ROWS;
  for (int x = threadIdx.x; x < ABK_ROWS * D; x += 64)
    rows[x >> 9][x & 511] = inp[(size_t)tb0 * D + x];
  __syncthreads();
  int j = threadIdx.x;
  if (j >= 3 * KMIX) return;
  int wj = j % KMIX;
  int which = j / KMIX;
  const float* W = (which == 0) ? Wa : ((which == 1) ? Wb : Wk);
  const float* B = (which == 0) ? ba : ((which == 1) ? bb_ : bk);
  float acc[ABK_ROWS];
  float bias = B[wj];
#pragma unroll
  for (int r = 0; r < ABK_ROWS; r++) acc[r] = bias;
  for (int i = 0; i < D; i++) {
    float wv = W[i * KMIX + wj];
#pragma unroll
    for (int r = 0; r < ABK_ROWS; r++) acc[r] += rows[r][i] * wv;
  }
  for (int r = 0; r < ABK_ROWS; r++) {
    int tb = tb0 + r;
    float v = acc[r];
    if (which == 0) alpha[tb * KMIX + wj] = v;
    else if (which == 1) beta[tb * KMIX + wj] = expf(v);
    else kinc[tb * KMIX + wj] = expf(v);
  }
}

// ---------------- K2: k cumsum over t; writes att_k region of d_out ----------------
__global__ __launch_bounds__(256) void cumsum_kernel(const float* __restrict__ att_init,
                                                     const float* __restrict__ kinc,
                                                     float* __restrict__ kout) {
  int idx = blockIdx.x * 256 + threadIdx.x;
  if (idx >= MB * KMIX) return;
  float k = att_init[idx];
  for (int t = 0; t < TS; t++) {
    k += kinc[t * MB * KMIX + idx];
    kout[t * MB * KMIX + idx] = k;
  }
}

// ---------------- K3: phi + w GEMM; writes att_w region of d_out ----------------
#define WT 16
__global__ __launch_bounds__(512) void phi_w_kernel(const float* __restrict__ c_inp,
                                                    const float* __restrict__ alpha,
                                                    const float* __restrict__ beta,
                                                    const float* __restrict__ katt,
                                                    float* __restrict__ wout) {
  int b  = blockIdx.x / (TS / WT);
  int t0 = (blockIdx.x % (TS / WT)) * WT;
  __shared__ float phi[WT][CTS];
  __shared__ float pa[WT][KMIX], pb[WT][KMIX], pk[WT][KMIX];
  for (int x = threadIdx.x; x < WT * KMIX; x += 512) {
    int tt = x / KMIX, j = x % KMIX;
    int tb = (t0 + tt) * MB + b;
    pa[tt][j] = alpha[tb * KMIX + j];
    pb[tt][j] = beta[tb * KMIX + j];
    pk[tt][j] = katt[tb * KMIX + j];
  }
  __syncthreads();
  {
    int c = threadIdx.x;
    float fc = (float)c;
#pragma unroll
    for (int tt = 0; tt < WT; tt++) {
      float s = 0.f;
#pragma unroll
      for (int j = 0; j < KMIX; j++) {
        float dd = pk[tt][j] - fc;
        s += expf(pa[tt][j] - pb[tt][j] * dd * dd);
      }
      phi[tt][c] = s;
    }
  }
  __syncthreads();
  {
    int d = threadIdx.x;
    float acc[WT];
#pragma unroll
    for (int tt = 0; tt < WT; tt++) acc[tt] = 0.f;
    const float* cb = c_inp + (size_t)b * D + d;
    for (int c2 = 0; c2 < CTS; c2++) {
      float cv = cb[(size_t)c2 * (MB * D)];
#pragma unroll
      for (int tt = 0; tt < WT; tt++) acc[tt] += phi[tt][c2] * cv;
    }
    for (int tt = 0; tt < WT; tt++)
      wout[((size_t)(t0 + tt) * MB + b) * D + d] = acc[tt];
  }
}

// ---------------- K4/K5: fp32 tiled GEMM, 128x128 tile ----------------
__global__ __launch_bounds__(256) void gemm128(const float* __restrict__ A,
                                               const float* __restrict__ B,
                                               const float* __restrict__ bias,
                                               const float* __restrict__ wadd,
                                               float* __restrict__ C,
                                               int Kdim, int ldb, int Nout, int remapHalf) {
  __shared__ float As[8][128];
  __shared__ float Bs[8][128];
  const int bm = blockIdx.x, bn = blockIdx.y;
  const int tid = threadIdx.x;
  const int tm = (tid >> 4) << 3;
  const int tn = (tid & 15) << 3;
  const int colOff = (remapHalf && bn >= 4) ? 512 : 0;
  const int n0 = bn * 128;
  float acc[8][8];
#pragma unroll
  for (int i = 0; i < 8; i++)
#pragma unroll
    for (int j = 0; j < 8; j++) acc[i][j] = 0.f;
  const int ar = tid >> 1;
  const int ak = (tid & 1) << 2;
  const int bkr = tid >> 5;
  const int bc = (tid & 31) << 2;
  const float* Aptr = A + (size_t)(bm * 128 + ar) * Kdim + ak;
  const float* Bptr = B + (size_t)bkr * ldb + n0 + colOff + bc;
  for (int k0 = 0; k0 < Kdim; k0 += 8) {
    float4 a4 = *(const float4*)(Aptr + k0);
    float4 b4 = *(const float4*)(Bptr + (size_t)k0 * ldb);
    As[ak + 0][ar] = a4.x; As[ak + 1][ar] = a4.y; As[ak + 2][ar] = a4.z; As[ak + 3][ar] = a4.w;
    *(float4*)&Bs[bkr][bc] = b4;
    __syncthreads();
#pragma unroll
    for (int kk = 0; kk < 8; kk++) {
      float a8[8], b8[8];
      *(float4*)&a8[0] = *(const float4*)&As[kk][tm];
      *(float4*)&a8[4] = *(const float4*)&As[kk][tm + 4];
      *(float4*)&b8[0] = *(const float4*)&Bs[kk][tn];
      *(float4*)&b8[4] = *(const float4*)&Bs[kk][tn + 4];
#pragma unroll
      for (int i = 0; i < 8; i++)
#pragma unroll
        for (int j = 0; j < 8; j++) acc[i][j] += a8[i] * b8[j];
    }
    __syncthreads();
  }
  float bb8[8];
#pragma unroll
  for (int j = 0; j < 8; j++) bb8[j] = bias[n0 + colOff + tn + j];
#pragma unroll
  for (int i = 0; i < 8; i++) {
    int m = bm * 128 + tm + i;
    size_t co = (size_t)m * Nout + n0 + tn;
    float v[8];
#pragma unroll
    for (int j = 0; j < 8; j++) v[j] = acc[i][j] + bb8[j];
    if (wadd) {
      float4 w0 = *(const float4*)&wadd[co];
      float4 w1 = *(const float4*)&wadd[co + 4];
      v[0] += w0.x; v[1] += w0.y; v[2] += w0.z; v[3] += w0.w;
      v[4] += w1.x; v[5] += w1.y; v[6] += w1.z; v[7] += w1.w;
    }
    *(float4*)&C[co]     = make_float4(v[0], v[1], v[2], v[3]);
    *(float4*)&C[co + 4] = make_float4(v[4], v[5], v[6], v[7]);
  }
}

// ---------------- K6: MFMA recurrence — streamed weights, pinned 4-deep prefetch ----
// Round-2 geometry (known 11.7us/step): 4 blocks x 512 thr, 16 batches/block, wave owns
// 4 n-tiles. Round-3 LDS layout (st_off/Lsrd, measured 0 conflicts). NEW: 4-deep
// ping-pong B-frag prefetch with IN-LOOP keep-alive asm (anchors loads at issue point —
// rounds 3/5 failure was the compiler sinking prefetch loads back to uses), and a
// never-idle port: matvec1 tail prefetches U[0..3], matvec2 tail prefetches Wr[0..3]
// for t+1, so the L2 stream continues through epilogues/barriers.

__device__ __forceinline__ int st_off(int m, int j) {
  int L = (((j >> 3) & 3) << 4) | m;
  int Ls = L ^ ((L >> 3) & 7);
  return ((j >> 5) << 10) + (Ls << 3) + (j & 7);
}

__device__ __forceinline__ float fast_sigmoid(float x) {
  return __builtin_amdgcn_rcpf(1.f + __expf(-x));
}
__device__ __forceinline__ float fast_tanh(float x) {
  x = fminf(15.f, fmaxf(-15.f, x));
  float e = __expf(2.f * x);
  return 1.f - 2.f * __builtin_amdgcn_rcpf(e + 1.f);
}

#define KEEP(x) asm volatile("" : "+v"(x))

__global__ __launch_bounds__(512, 2) void recurrence_mfma(
    const float* __restrict__ F2,
    const bf16x8* __restrict__ WrPK,
    const bf16x8* __restrict__ UPK,
    const float* __restrict__ gru_init,
    float* __restrict__ hout) {
  __shared__ unsigned short hbf[16 * 1024];
  __shared__ unsigned short srbf[16 * 1024];
  const int tid  = threadIdx.x;
  const int wave = tid >> 6;        // 0..7
  const int lane = tid & 63;
  const int lg = lane >> 4;
  const int ln = lane & 15;
  const int b0 = blockIdx.x * 16;
  const int Lsrd = lane ^ ((lane >> 3) & 7);   // swizzled read chunk for A-frags

  // Per-wave fragment base pointers. frag (nt, kt) at base[kt<<6] with base = PK + (nt*16<<6) + lane.
  const bf16x8* wr0 = WrPK + (((wave * 4 + 0) * 16) << 6) + lane;
  const bf16x8* wr1 = WrPK + (((wave * 4 + 1) * 16) << 6) + lane;
  const bf16x8* wr2 = WrPK + (((wave * 4 + 2) * 16) << 6) + lane;
  const bf16x8* wr3 = WrPK + (((wave * 4 + 3) * 16) << 6) + lane;
  const bf16x8* u0  = UPK  + (((wave * 4 + 0) * 16) << 6) + lane;
  const bf16x8* u1  = UPK  + (((wave * 4 + 1) * 16) << 6) + lane;
  const bf16x8* u2  = UPK  + (((wave * 4 + 2) * 16) << 6) + lane;
  const bf16x8* u3  = UPK  + (((wave * 4 + 3) * 16) << 6) + lane;

  // ---- init h: fp32 master in regs, bf16 copy in LDS (st_off layout) ----
  float hreg[4][4];   // [q][r]: m = lg*4+r, j = (wave*4+q)*16+ln
#pragma unroll
  for (int q = 0; q < 4; q++) {
    int j = ((wave * 4 + q) << 4) + ln;
#pragma unroll
    for (int r = 0; r < 4; r++) {
      int m = (lg << 2) + r;
      float v = gru_init[(b0 + m) * D + j];
      hreg[q][r] = v;
      hbf[st_off(m, j)] = f2bf(v);
    }
  }
  __syncthreads();

  // ---- prologue: fill 4-deep prefetch buffer with Wr[0..3] ----
  bf16x8 buf[4][4];
#pragma unroll
  for (int p = 0; p < 4; p++) {
    buf[p][0] = wr0[p << 6]; KEEP(buf[p][0]);
    buf[p][1] = wr1[p << 6]; KEEP(buf[p][1]);
    buf[p][2] = wr2[p << 6]; KEEP(buf[p][2]);
    buf[p][3] = wr3[p << 6]; KEEP(buf[p][3]);
  }

  const f32x4 zero4 = {0.f, 0.f, 0.f, 0.f};
#pragma unroll 1
  for (int t = 0; t < TS; t++) {
    // s/g loads for this step (consumed after matvec1 — latency hidden under stream)
    const float* f2 = F2 + ((size_t)t * MB + b0) * 1024;
    float sreg[4][4], greg[4][4];
#pragma unroll
    for (int q = 0; q < 4; q++) {
      int j = ((wave * 4 + q) << 4) + ln;
#pragma unroll
      for (int r = 0; r < 4; r++) {
        int m = (lg << 2) + r;
        sreg[q][r] = f2[m * 1024 + j];
        greg[q][r] = f2[m * 1024 + 512 + j];
      }
    }
    // ---- matvec1: c1 = h @ Wr ; tail prefetches U[0..3] ----
    f32x4 c1[4] = {zero4, zero4, zero4, zero4};
#pragma unroll
    for (int kt = 0; kt < 16; kt++) {
      const int slot = kt & 3;
      bf16x8 g0 = buf[slot][0], g1 = buf[slot][1], g2 = buf[slot][2], g3 = buf[slot][3];
      if (kt < 12) {
        buf[slot][0] = wr0[(kt + 4) << 6]; KEEP(buf[slot][0]);
        buf[slot][1] = wr1[(kt + 4) << 6]; KEEP(buf[slot][1]);
        buf[slot][2] = wr2[(kt + 4) << 6]; KEEP(buf[slot][2]);
        buf[slot][3] = wr3[(kt + 4) << 6]; KEEP(buf[slot][3]);
      } else {
        buf[slot][0] = u0[(kt - 12) << 6]; KEEP(buf[slot][0]);
        buf[slot][1] = u1[(kt - 12) << 6]; KEEP(buf[slot][1]);
        buf[slot][2] = u2[(kt - 12) << 6]; KEEP(buf[slot][2]);
        buf[slot][3] = u3[(kt - 12) << 6]; KEEP(buf[slot][3]);
      }
      bf16x8 a = *(const bf16x8*)(hbf + (kt << 10) + (Lsrd << 3));
      c1[0] = __builtin_amdgcn_mfma_f32_16x16x32_bf16(a, g0, c1[0], 0, 0, 0);
      c1[1] = __builtin_amdgcn_mfma_f32_16x16x32_bf16(a, g1, c1[1], 0, 0, 0);
      c1[2] = __builtin_amdgcn_mfma_f32_16x16x32_bf16(a, g2, c1[2], 0, 0, 0);
      c1[3] = __builtin_amdgcn_mfma_f32_16x16x32_bf16(a, g3, c1[3], 0, 0, 0);
    }
    // ---- epilogue 1: sr = s * sigmoid(c1 + g) ----
#pragma unroll
    for (int q = 0; q < 4; q++) {
      int j = ((wave * 4 + q) << 4) + ln;
#pragma unroll
      for (int r = 0; r < 4; r++) {
        int m = (lg << 2) + r;
        float rr = fast_sigmoid(c1[q][r] + greg[q][r]);
        srbf[st_off(m, j)] = f2bf(sreg[q][r] * rr);
      }
    }
    __syncthreads();
    // ---- matvec2: c2 = sr @ U ; tail prefetches Wr[0..3] for t+1 ----
    f32x4 c2[4] = {zero4, zero4, zero4, zero4};
#pragma unroll
    for (int kt = 0; kt < 16; kt++) {
      const int slot = kt & 3;
      bf16x8 g0 = buf[slot][0], g1 = buf[slot][1], g2 = buf[slot][2], g3 = buf[slot][3];
      if (kt < 12) {
        buf[slot][0] = u0[(kt + 4) << 6]; KEEP(buf[slot][0]);
        buf[slot][1] = u1[(kt + 4) << 6]; KEEP(buf[slot][1]);
        buf[slot][2] = u2[(kt + 4) << 6]; KEEP(buf[slot][2]);
        buf[slot][3] = u3[(kt + 4) << 6]; KEEP(buf[slot][3]);
      } else {
        buf[slot][0] = wr0[(kt - 12) << 6]; KEEP(buf[slot][0]);
        buf[slot][1] = wr1[(kt - 12) << 6]; KEEP(buf[slot][1]);
        buf[slot][2] = wr2[(kt - 12) << 6]; KEEP(buf[slot][2]);
        buf[slot][3] = wr3[(kt - 12) << 6]; KEEP(buf[slot][3]);
      }
      bf16x8 a = *(const bf16x8*)(srbf + (kt << 10) + (Lsrd << 3));
      c2[0] = __builtin_amdgcn_mfma_f32_16x16x32_bf16(a, g0, c2[0], 0, 0, 0);
      c2[1] = __builtin_amdgcn_mfma_f32_16x16x32_bf16(a, g1, c2[1], 0, 0, 0);
      c2[2] = __builtin_amdgcn_mfma_f32_16x16x32_bf16(a, g2, c2[2], 0, 0, 0);
      c2[3] = __builtin_amdgcn_mfma_f32_16x16x32_bf16(a, g3, c2[3], 0, 0, 0);
    }
    // ---- epilogue 2: h += 1 + tanh(c2 + s); write hout + hbf ----
#pragma unroll
    for (int q = 0; q < 4; q++) {
      int j = ((wave * 4 + q) << 4) + ln;
#pragma unroll
      for (int r = 0; r < 4; r++) {
        int m = (lg << 2) + r;
        float hn = hreg[q][r] + 1.f + fast_tanh(c2[q][r] + sreg[q][r]);
        hreg[q][r] = hn;
        hout[((size_t)t * MB + (b0 + m)) * D + j] = hn;
        hbf[st_off(m, j)] = f2bf(hn);
      }
    }
    __syncthreads();
  }
}

extern "C" void kernel_launch(void* const* d_in, const int* in_sizes, int n_in,
                              void* d_out, int out_size, void* d_ws, size_t ws_size,
                              hipStream_t stream) {
  const float* c_inp    = (const float*)d_in[0];
  const float* inp      = (const float*)d_in[1];
  const float* gru_init = (const float*)d_in[2];
  const float* att_init = (const float*)d_in[3];
  const float* Wa   = (const float*)d_in[4];
  const float* ba   = (const float*)d_in[5];
  const float* Wb   = (const float*)d_in[6];
  const float* bb   = (const float*)d_in[7];
  const float* Wk   = (const float*)d_in[8];
  const float* bk   = (const float*)d_in[9];
  const float* Wif  = (const float*)d_in[10];
  const float* bif  = (const float*)d_in[11];
  const float* Wfork= (const float*)d_in[12];
  const float* bfork= (const float*)d_in[13];
  const float* Wur  = (const float*)d_in[14];
  const float* U    = (const float*)d_in[15];

  float* out = (float*)d_out;
  float* hid  = out;
  float* attk = out + ATTK_OFF;
  float* attw = out + ATTW_OFF;

  char* ws = (char*)d_ws;
  unsigned short* WrPK = (unsigned short*)(ws + WS_WRPK);
  unsigned short* UPK  = (unsigned short*)(ws + WS_UPK);
  float* alpha = (float*)(ws + WS_ALPHA);
  float* beta  = (float*)(ws + WS_BETA);
  float* kinc  = (float*)(ws + WS_KINC);
  float* X     = (float*)(ws + WS_X);
  float* F2    = (float*)(ws + WS_F2);

  hipLaunchKernelGGL(pack_weights, dim3(1024), dim3(256), 0, stream, Wur, U, WrPK, UPK);
  hipLaunchKernelGGL(abk_kernel, dim3(TS * MB / ABK_ROWS), dim3(64), 0, stream,
                     inp, Wa, ba, Wb, bb, Wk, bk, alpha, beta, kinc);
  hipLaunchKernelGGL(cumsum_kernel, dim3((MB * KMIX + 255) / 256), dim3(256), 0, stream,
                     att_init, kinc, attk);
  hipLaunchKernelGGL(phi_w_kernel, dim3(MB * (TS / WT)), dim3(512), 0, stream,
                     c_inp, alpha, beta, attk, attw);
  hipLaunchKernelGGL(gemm128, dim3(TS * MB / 128, D / 128), dim3(256), 0, stream,
                     inp, Wif, bif, attw, X, D, D, D, 0);
  hipLaunchKernelGGL(gemm128, dim3(TS * MB / 128, 1024 / 128), dim3(256), 0, stream,
                     X, Wfork, bfork, (const float*)nullptr, F2, D, 3 * D, 1024, 1);
  hipLaunchKernelGGL(recurrence_mfma, dim3(4), dim3(512), 0, stream,
                     F2, (const bf16x8*)WrPK, (const bf16x8*)UPK, gru_init, hid);
}

// Round 10
// 4095.671 us; speedup vs baseline: 1.8392x; 1.8392x over previous
//
#include <hip/hip_runtime.h>
#include <hip/hip_bf16.h>
#include <math.h>

#define TS   256
#define CTS  512
#define MB   64
#define D    512
#define KMIX 20

// d_out layout (floats): hiddens [TS][MB][D], att_k [TS][MB][KMIX], att_w [TS][MB][D]
#define HID_SIZE  (TS*MB*D)
#define ATTK_OFF  (HID_SIZE)
#define ATTW_OFF  (HID_SIZE + TS*MB*KMIX)

// ws layout (bytes):
#define WS_WRPK8 0            // 262144  (i8 packed reset-Wur)
#define WS_UPK8  262144       // 262144  (i8 packed U)
#define WS_WSC   524288       // 4096    (wscWr[512], wscU[512] f32)
#define WS_ALPHA 1048576
#define WS_BETA  2359296
#define WS_KINC  3670016
#define WS_X     5242880
#define WS_F2    38797312

typedef __attribute__((ext_vector_type(2))) long long ll2;
typedef __attribute__((ext_vector_type(4))) int i32x4;

// ---------------- K0a: per-output-column weight scales ----------------
__global__ __launch_bounds__(256) void col_scales(const float* __restrict__ Wur,
                                                  const float* __restrict__ U,
                                                  float* __restrict__ wscWr,
                                                  float* __restrict__ wscU) {
  int j = blockIdx.x * 256 + threadIdx.x;
  if (j >= 512) return;
  float mw = 0.f, mu = 0.f;
  for (int k = 0; k < 512; k++) {
    mw = fmaxf(mw, fabsf(Wur[k * 1024 + 512 + j]));
    mu = fmaxf(mu, fabsf(U[k * 512 + j]));
  }
  wscWr[j] = fmaxf(mw, 1e-20f) * (1.0f / 127.0f);
  wscU[j]  = fmaxf(mu, 1e-20f) * (1.0f / 127.0f);
}

// ---------------- K0b: pack weights to i8, MFMA B-frag PAIR-interleaved layout ----------
// byte o = ((nt*8 + p)*64 + l)*16 + half*8 + e  <->  B[k][n],
//   k = (2p+half)*32 + ((l>>4)&3)*8 + e ; n = nt*16 + (l&15).
__global__ __launch_bounds__(256) void pack_weights_i8(const float* __restrict__ Wur,
                                                       const float* __restrict__ U,
                                                       const float* __restrict__ wscWr,
                                                       const float* __restrict__ wscU,
                                                       signed char* __restrict__ WrPK8,
                                                       signed char* __restrict__ UPK8) {
  int o = blockIdx.x * 256 + threadIdx.x;   // 0..262143
  int e = o & 7, half = (o >> 3) & 1, l = (o >> 4) & 63, p = (o >> 10) & 7, nt = o >> 13;
  int k = (2 * p + half) * 32 + ((l >> 4) & 3) * 8 + e;
  int n = nt * 16 + (l & 15);
  float i1 = __builtin_amdgcn_rcpf(wscWr[n]);
  float i2 = __builtin_amdgcn_rcpf(wscU[n]);
  int q1 = __float2int_rn(Wur[k * 1024 + 512 + n] * i1);
  int q2 = __float2int_rn(U[k * 512 + n] * i2);
  q1 = q1 > 127 ? 127 : (q1 < -127 ? -127 : q1);
  q2 = q2 > 127 ? 127 : (q2 < -127 ? -127 : q2);
  WrPK8[o] = (signed char)q1;
  UPK8[o]  = (signed char)q2;
}

// ---------------- K1: alpha = inp@Wa+ba (log domain), beta, kinc ----------------
#define ABK_ROWS 8
__global__ __launch_bounds__(64) void abk_kernel(const float* __restrict__ inp,
                                                 const float* __restrict__ Wa, const float* __restrict__ ba,
                                                 const float* __restrict__ Wb, const float* __restrict__ bb_,
                                                 const float* __restrict__ Wk, const float* __restrict__ bk,
                                                 float* __restrict__ alpha, float* __restrict__ beta,
                                                 float* __restrict__ kinc) {
  __shared__ float rows[ABK_ROWS][D];
  int tb0 = blockIdx.x * ABK_ROWS;
  for (int x = threadIdx.x; x < ABK_ROWS * D; x += 64)
    rows[x >> 9][x & 511] = inp[(size_t)tb0 * D + x];
  __syncthreads();
  int j = threadIdx.x;
  if (j >= 3 * KMIX) return;
  int wj = j % KMIX;
  int which = j / KMIX;
  const float* W = (which == 0) ? Wa : ((which == 1) ? Wb : Wk);
  const float* B = (which == 0) ? ba : ((which == 1) ? bb_ : bk);
  float acc[ABK_ROWS];
  float bias = B[wj];
#pragma unroll
  for (int r = 0; r < ABK_ROWS; r++) acc[r] = bias;
  for (int i = 0; i < D; i++) {
    float wv = W[i * KMIX + wj];
#pragma unroll
    for (int r = 0; r < ABK_ROWS; r++) acc[r] += rows[r][i] * wv;
  }
  for (int r = 0; r < ABK_ROWS; r++) {
    int tb = tb0 + r;
    float v = acc[r];
    if (which == 0) alpha[tb * KMIX + wj] = v;
    else if (which == 1) beta[tb * KMIX + wj] = expf(v);
    else kinc[tb * KMIX + wj] = expf(v);
  }
}

// ---------------- K2: k cumsum over t; writes att_k region of d_out ----------------
__global__ __launch_bounds__(256) void cumsum_kernel(const float* __restrict__ att_init,
                                                     const float* __restrict__ kinc,
                                                     float* __restrict__ kout) {
  int idx = blockIdx.x * 256 + threadIdx.x;
  if (idx >= MB * KMIX) return;
  float k = att_init[idx];
  for (int t = 0; t < TS; t++) {
    k += kinc[t * MB * KMIX + idx];
    kout[t * MB * KMIX + idx] = k;
  }
}

// ---------------- K3: phi + w GEMM; writes att_w region of d_out ----------------
#define WT 16
__global__ __launch_bounds__(512) void phi_w_kernel(const float* __restrict__ c_inp,
                                                    const float* __restrict__ alpha,
                                                    const float* __restrict__ beta,
                                                    const float* __restrict__ katt,
                                                    float* __restrict__ wout) {
  int b  = blockIdx.x / (TS / WT);
  int t0 = (blockIdx.x % (TS / WT)) * WT;
  __shared__ float phi[WT][CTS];
  __shared__ float pa[WT][KMIX], pb[WT][KMIX], pk[WT][KMIX];
  for (int x = threadIdx.x; x < WT * KMIX; x += 512) {
    int tt = x / KMIX, j = x % KMIX;
    int tb = (t0 + tt) * MB + b;
    pa[tt][j] = alpha[tb * KMIX + j];
    pb[tt][j] = beta[tb * KMIX + j];
    pk[tt][j] = katt[tb * KMIX + j];
  }
  __syncthreads();
  {
    int c = threadIdx.x;
    float fc = (float)c;
#pragma unroll
    for (int tt = 0; tt < WT; tt++) {
      float s = 0.f;
#pragma unroll
      for (int j = 0; j < KMIX; j++) {
        float dd = pk[tt][j] - fc;
        s += expf(pa[tt][j] - pb[tt][j] * dd * dd);
      }
      phi[tt][c] = s;
    }
  }
  __syncthreads();
  {
    int d = threadIdx.x;
    float acc[WT];
#pragma unroll
    for (int tt = 0; tt < WT; tt++) acc[tt] = 0.f;
    const float* cb = c_inp + (size_t)b * D + d;
    for (int c2 = 0; c2 < CTS; c2++) {
      float cv = cb[(size_t)c2 * (MB * D)];
#pragma unroll
      for (int tt = 0; tt < WT; tt++) acc[tt] += phi[tt][c2] * cv;
    }
    for (int tt = 0; tt < WT; tt++)
      wout[((size_t)(t0 + tt) * MB + b) * D + d] = acc[tt];
  }
}

// ---------------- K4/K5: fp32 tiled GEMM, 128x128 tile ----------------
__global__ __launch_bounds__(256) void gemm128(const float* __restrict__ A,
                                               const float* __restrict__ B,
                                               const float* __restrict__ bias,
                                               const float* __restrict__ wadd,
                                               float* __restrict__ C,
                                               int Kdim, int ldb, int Nout, int remapHalf) {
  __shared__ float As[8][128];
  __shared__ float Bs[8][128];
  const int bm = blockIdx.x, bn = blockIdx.y;
  const int tid = threadIdx.x;
  const int tm = (tid >> 4) << 3;
  const int tn = (tid & 15) << 3;
  const int colOff = (remapHalf && bn >= 4) ? 512 : 0;
  const int n0 = bn * 128;
  float acc[8][8];
#pragma unroll
  for (int i = 0; i < 8; i++)
#pragma unroll
    for (int j = 0; j < 8; j++) acc[i][j] = 0.f;
  const int ar = tid >> 1;
  const int ak = (tid & 1) << 2;
  const int bkr = tid >> 5;
  const int bc = (tid & 31) << 2;
  const float* Aptr = A + (size_t)(bm * 128 + ar) * Kdim + ak;
  const float* Bptr = B + (size_t)bkr * ldb + n0 + colOff + bc;
  for (int k0 = 0; k0 < Kdim; k0 += 8) {
    float4 a4 = *(const float4*)(Aptr + k0);
    float4 b4 = *(const float4*)(Bptr + (size_t)k0 * ldb);
    As[ak + 0][ar] = a4.x; As[ak + 1][ar] = a4.y; As[ak + 2][ar] = a4.z; As[ak + 3][ar] = a4.w;
    *(float4*)&Bs[bkr][bc] = b4;
    __syncthreads();
#pragma unroll
    for (int kk = 0; kk < 8; kk++) {
      float a8[8], b8[8];
      *(float4*)&a8[0] = *(const float4*)&As[kk][tm];
      *(float4*)&a8[4] = *(const float4*)&As[kk][tm + 4];
      *(float4*)&b8[0] = *(const float4*)&Bs[kk][tn];
      *(float4*)&b8[4] = *(const float4*)&Bs[kk][tn + 4];
#pragma unroll
      for (int i = 0; i < 8; i++)
#pragma unroll
        for (int j = 0; j < 8; j++) acc[i][j] += a8[i] * b8[j];
    }
    __syncthreads();
  }
  float bb8[8];
#pragma unroll
  for (int j = 0; j < 8; j++) bb8[j] = bias[n0 + colOff + tn + j];
#pragma unroll
  for (int i = 0; i < 8; i++) {
    int m = bm * 128 + tm + i;
    size_t co = (size_t)m * Nout + n0 + tn;
    float v[8];
#pragma unroll
    for (int j = 0; j < 8; j++) v[j] = acc[i][j] + bb8[j];
    if (wadd) {
      float4 w0 = *(const float4*)&wadd[co];
      float4 w1 = *(const float4*)&wadd[co + 4];
      v[0] += w0.x; v[1] += w0.y; v[2] += w0.z; v[3] += w0.w;
      v[4] += w1.x; v[5] += w1.y; v[6] += w1.z; v[7] += w1.w;
    }
    *(float4*)&C[co]     = make_float4(v[0], v[1], v[2], v[3]);
    *(float4*)&C[co + 4] = make_float4(v[4], v[5], v[6], v[7]);
  }
}

// ---------------- K6: i8 MFMA recurrence, round-2 structure (plain inline loads) ----
// 4 blocks x 512 thr (8 waves), 16 batches/block, wave owns 4 n-tiles. Weights streamed
// from L2 each step: 512 KB (i8) via dwordx4 pair-loads — half the bytes AND half the
// load instructions of the bf16 round-2 kernel. No asm scheduling (rounds 3-9 lesson:
// compiler's natural schedule wins). Per-step h scale (h in [0, 2t]); per-column weight
// scales; sr on fixed +-8 scale.
// A-buffer (LDS, 8KB each): byte (page, l, half, e) = A[m=l&15][k=(2*page+half)*32+((l>>4)&3)*8+e].

__device__ __forceinline__ int a8off(int m, int j) {
  return ((j >> 6) << 10) + (((((j >> 3) & 3) << 4) + m) << 4) + (((j >> 5) & 1) << 3) + (j & 7);
}

__device__ __forceinline__ float fast_sigmoid(float x) {
  return __builtin_amdgcn_rcpf(1.f + __expf(-x));
}
__device__ __forceinline__ float fast_tanh(float x) {
  x = fminf(15.f, fmaxf(-15.f, x));
  float e = __expf(2.f * x);
  return 1.f - 2.f * __builtin_amdgcn_rcpf(e + 1.f);
}

__global__ __launch_bounds__(512, 2) void recurrence_i8(
    const float* __restrict__ F2,
    const signed char* __restrict__ WrPK8,
    const signed char* __restrict__ UPK8,
    const float* __restrict__ wscWr,
    const float* __restrict__ wscU,
    const float* __restrict__ gru_init,
    float* __restrict__ hout) {
  __shared__ long long hq8[1024];    // 8KB i8 A-buffer (h)
  __shared__ long long srq8[1024];   // 8KB i8 A-buffer (sr)
  signed char* hqc  = (signed char*)hq8;
  signed char* srqc = (signed char*)srq8;
  const int tid  = threadIdx.x;
  const int wave = tid >> 6;        // 0..7
  const int lane = tid & 63;
  const int lg = lane >> 4;
  const int ln = lane & 15;
  const int b0 = blockIdx.x * 16;

  // per-wave B base pointers (pair-interleaved layout), lane folded in
  const signed char* wrq0 = WrPK8 + (size_t)(wave * 4 + 0) * 8192 + lane * 16;
  const signed char* wrq1 = WrPK8 + (size_t)(wave * 4 + 1) * 8192 + lane * 16;
  const signed char* wrq2 = WrPK8 + (size_t)(wave * 4 + 2) * 8192 + lane * 16;
  const signed char* wrq3 = WrPK8 + (size_t)(wave * 4 + 3) * 8192 + lane * 16;
  const signed char* uq0  = UPK8  + (size_t)(wave * 4 + 0) * 8192 + lane * 16;
  const signed char* uq1  = UPK8  + (size_t)(wave * 4 + 1) * 8192 + lane * 16;
  const signed char* uq2  = UPK8  + (size_t)(wave * 4 + 2) * 8192 + lane * 16;
  const signed char* uq3  = UPK8  + (size_t)(wave * 4 + 3) * 8192 + lane * 16;

  // per-thread output-column dequant scales (j_q = (wave*4+q)*16 + ln)
  float wscWrR[4], wscUR[4];
#pragma unroll
  for (int q = 0; q < 4; q++) {
    int j = ((wave * 4 + q) << 4) + ln;
    wscWrR[q] = wscWr[j];
    wscUR[q]  = wscU[j];
  }

  // ---- init h: fp32 master in regs, i8 copy in LDS ----
  float hreg[4][4];
  float hdq = 2.0f / 127.0f;         // dequant scale matching initial quant bound 2
  {
    float hqi = 127.0f / 2.0f;
#pragma unroll
    for (int q = 0; q < 4; q++) {
      int j = ((wave * 4 + q) << 4) + ln;
#pragma unroll
      for (int r = 0; r < 4; r++) {
        int m = (lg << 2) + r;
        float v = gru_init[(b0 + m) * D + j];
        hreg[q][r] = v;
        int qv = __float2int_rn(v * hqi);
        qv = qv > 127 ? 127 : (qv < -127 ? -127 : qv);
        hqc[a8off(m, j)] = (signed char)qv;
      }
    }
  }
  __syncthreads();

  const i32x4 z4 = {0, 0, 0, 0};
#pragma unroll 1
  for (int t = 0; t < TS; t++) {
    // s/g loads for this step (consumed after matvec1 — hidden under the stream)
    const float* f2 = F2 + ((size_t)t * MB + b0) * 1024;
    float sreg[4][4], greg[4][4];
#pragma unroll
    for (int q = 0; q < 4; q++) {
      int j = ((wave * 4 + q) << 4) + ln;
#pragma unroll
      for (int r = 0; r < 4; r++) {
        int m = (lg << 2) + r;
        sreg[q][r] = f2[m * 1024 + j];
        greg[q][r] = f2[m * 1024 + 512 + j];
      }
    }
    // ---- matvec1: c1 = h @ Wr (i8, K=32, frag-pairs) ----
    i32x4 c1[4] = {z4, z4, z4, z4};
#pragma unroll
    for (int p = 0; p < 8; p++) {
      ll2 a2 = *(const ll2*)(hqc + (p << 10) + (lane << 4));
      ll2 w0 = *(const ll2*)(wrq0 + (p << 10));
      ll2 w1 = *(const ll2*)(wrq1 + (p << 10));
      ll2 w2 = *(const ll2*)(wrq2 + (p << 10));
      ll2 w3 = *(const ll2*)(wrq3 + (p << 10));
      c1[0] = __builtin_amdgcn_mfma_i32_16x16x32_i8(a2[0], w0[0], c1[0], 0, 0, 0);
      c1[0] = __builtin_amdgcn_mfma_i32_16x16x32_i8(a2[1], w0[1], c1[0], 0, 0, 0);
      c1[1] = __builtin_amdgcn_mfma_i32_16x16x32_i8(a2[0], w1[0], c1[1], 0, 0, 0);
      c1[1] = __builtin_amdgcn_mfma_i32_16x16x32_i8(a2[1], w1[1], c1[1], 0, 0, 0);
      c1[2] = __builtin_amdgcn_mfma_i32_16x16x32_i8(a2[0], w2[0], c1[2], 0, 0, 0);
      c1[2] = __builtin_amdgcn_mfma_i32_16x16x32_i8(a2[1], w2[1], c1[2], 0, 0, 0);
      c1[3] = __builtin_amdgcn_mfma_i32_16x16x32_i8(a2[0], w3[0], c1[3], 0, 0, 0);
      c1[3] = __builtin_amdgcn_mfma_i32_16x16x32_i8(a2[1], w3[1], c1[3], 0, 0, 0);
    }
    // ---- epilogue 1: sr = s * sigmoid(dequant(c1) + g), quantize to i8 (+-8 range) ----
#pragma unroll
    for (int q = 0; q < 4; q++) {
      int j = ((wave * 4 + q) << 4) + ln;
      float d1 = hdq * wscWrR[q];
#pragma unroll
      for (int r = 0; r < 4; r++) {
        int m = (lg << 2) + r;
        float c1f = (float)c1[q][r] * d1;
        float rr = fast_sigmoid(c1f + greg[q][r]);
        float sr = sreg[q][r] * rr;
        int qv = __float2int_rn(sr * (127.0f / 8.0f));
        qv = qv > 127 ? 127 : (qv < -127 ? -127 : qv);
        srqc[a8off(m, j)] = (signed char)qv;
      }
    }
    __syncthreads();
    // ---- matvec2: c2 = sr @ U ----
    i32x4 c2[4] = {z4, z4, z4, z4};
#pragma unroll
    for (int p = 0; p < 8; p++) {
      ll2 a2 = *(const ll2*)(srqc + (p << 10) + (lane << 4));
      ll2 w0 = *(const ll2*)(uq0 + (p << 10));
      ll2 w1 = *(const ll2*)(uq1 + (p << 10));
      ll2 w2 = *(const ll2*)(uq2 + (p << 10));
      ll2 w3 = *(const ll2*)(uq3 + (p << 10));
      c2[0] = __builtin_amdgcn_mfma_i32_16x16x32_i8(a2[0], w0[0], c2[0], 0, 0, 0);
      c2[0] = __builtin_amdgcn_mfma_i32_16x16x32_i8(a2[1], w0[1], c2[0], 0, 0, 0);
      c2[1] = __builtin_amdgcn_mfma_i32_16x16x32_i8(a2[0], w1[0], c2[1], 0, 0, 0);
      c2[1] = __builtin_amdgcn_mfma_i32_16x16x32_i8(a2[1], w1[1], c2[1], 0, 0, 0);
      c2[2] = __builtin_amdgcn_mfma_i32_16x16x32_i8(a2[0], w2[0], c2[2], 0, 0, 0);
      c2[2] = __builtin_amdgcn_mfma_i32_16x16x32_i8(a2[1], w2[1], c2[2], 0, 0, 0);
      c2[3] = __builtin_amdgcn_mfma_i32_16x16x32_i8(a2[0], w3[0], c2[3], 0, 0, 0);
      c2[3] = __builtin_amdgcn_mfma_i32_16x16x32_i8(a2[1], w3[1], c2[3], 0, 0, 0);
    }
    // ---- epilogue 2: h += 1 + tanh(dequant(c2) + s); write hout + quantized h ----
    {
      float hbn = 2.0f * (float)(t + 1) + 2.0f;
      float hqin = 127.0f / hbn;
#pragma unroll
      for (int q = 0; q < 4; q++) {
        int j = ((wave * 4 + q) << 4) + ln;
        float d2 = (8.0f / 127.0f) * wscUR[q];
#pragma unroll
        for (int r = 0; r < 4; r++) {
          int m = (lg << 2) + r;
          float c2f = (float)c2[q][r] * d2;
          float hn = hreg[q][r] + 1.f + fast_tanh(c2f + sreg[q][r]);
          hreg[q][r] = hn;
          hout[((size_t)t * MB + (b0 + m)) * D + j] = hn;
          int qv = __float2int_rn(hn * hqin);
          qv = qv > 127 ? 127 : (qv < -127 ? -127 : qv);
          hqc[a8off(m, j)] = (signed char)qv;
        }
      }
      hdq = hbn * (1.0f / 127.0f);
    }
    __syncthreads();
  }
}

extern "C" void kernel_launch(void* const* d_in, const int* in_sizes, int n_in,
                              void* d_out, int out_size, void* d_ws, size_t ws_size,
                              hipStream_t stream) {
  const float* c_inp    = (const float*)d_in[0];
  const float* inp      = (const float*)d_in[1];
  const float* gru_init = (const float*)d_in[2];
  const float* att_init = (const float*)d_in[3];
  const float* Wa   = (const float*)d_in[4];
  const float* ba   = (const float*)d_in[5];
  const float* Wb   = (const float*)d_in[6];
  const float* bb   = (const float*)d_in[7];
  const float* Wk   = (const float*)d_in[8];
  const float* bk   = (const float*)d_in[9];
  const float* Wif  = (const float*)d_in[10];
  const float* bif  = (const float*)d_in[11];
  const float* Wfork= (const float*)d_in[12];
  const float* bfork= (const float*)d_in[13];
  const float* Wur  = (const float*)d_in[14];
  const float* U    = (const float*)d_in[15];

  float* out = (float*)d_out;
  float* hid  = out;
  float* attk = out + ATTK_OFF;
  float* attw = out + ATTW_OFF;

  char* ws = (char*)d_ws;
  signed char* WrPK8 = (signed char*)(ws + WS_WRPK8);
  signed char* UPK8  = (signed char*)(ws + WS_UPK8);
  float* wscWr = (float*)(ws + WS_WSC);
  float* wscU  = (float*)(ws + WS_WSC + 2048);
  float* alpha = (float*)(ws + WS_ALPHA);
  float* beta  = (float*)(ws + WS_BETA);
  float* kinc  = (float*)(ws + WS_KINC);
  float* X     = (float*)(ws + WS_X);
  float* F2    = (float*)(ws + WS_F2);

  hipLaunchKernelGGL(col_scales, dim3(2), dim3(256), 0, stream, Wur, U, wscWr, wscU);
  hipLaunchKernelGGL(pack_weights_i8, dim3(1024), dim3(256), 0, stream,
                     Wur, U, wscWr, wscU, WrPK8, UPK8);
  hipLaunchKernelGGL(abk_kernel, dim3(TS * MB / ABK_ROWS), dim3(64), 0, stream,
                     inp, Wa, ba, Wb, bb, Wk, bk, alpha, beta, kinc);
  hipLaunchKernelGGL(cumsum_kernel, dim3((MB * KMIX + 255) / 256), dim3(256), 0, stream,
                     att_init, kinc, attk);
  hipLaunchKernelGGL(phi_w_kernel, dim3(MB * (TS / WT)), dim3(512), 0, stream,
                     c_inp, alpha, beta, attk, attw);
  hipLaunchKernelGGL(gemm128, dim3(TS * MB / 128, D / 128), dim3(256), 0, stream,
                     inp, Wif, bif, attw, X, D, D, D, 0);
  hipLaunchKernelGGL(gemm128, dim3(TS * MB / 128, 1024 / 128), dim3(256), 0, stream,
                     X, Wfork, bfork, (const float*)nullptr, F2, D, 3 * D, 1024, 1);
  hipLaunchKernelGGL(recurrence_i8, dim3(4), dim3(512), 0, stream,
                     F2, WrPK8, UPK8, wscWr, wscU, gru_init, hid);
}

// Round 11
// 3275.367 us; speedup vs baseline: 2.2998x; 1.2504x over previous
//
#include <hip/hip_runtime.h>
#include <hip/hip_bf16.h>
#include <math.h>

#define TS   256
#define CTS  512
#define MB   64
#define D    512
#define KMIX 20

// d_out layout (floats): hiddens [TS][MB][D], att_k [TS][MB][KMIX], att_w [TS][MB][D]
#define HID_SIZE  (TS*MB*D)
#define ATTK_OFF  (HID_SIZE)
#define ATTW_OFF  (HID_SIZE + TS*MB*KMIX)

// ws layout (bytes):
#define WS_WRPK8 0            // 262144  (i8 packed reset-Wur)
#define WS_UPK8  262144       // 262144  (i8 packed U)
#define WS_WSC   524288       // 4096    (wscWr[512], wscU[512] f32)
#define WS_ALPHA 1048576
#define WS_BETA  2359296
#define WS_KINC  3670016
#define WS_X     5242880      // X (f32, 33.5MB) -> reused as F2T (bf16, 33.5MB) after gemm#2
#define WS_F2    38797312

typedef __attribute__((ext_vector_type(2))) long long ll2;
typedef __attribute__((ext_vector_type(4))) int i32x4;
typedef __attribute__((ext_vector_type(8))) unsigned short ushort8;

__device__ __forceinline__ unsigned short f2bf(float v) {
  __hip_bfloat16 h = __float2bfloat16(v);
  union { __hip_bfloat16 h; unsigned short u; } cvt; cvt.h = h;
  return cvt.u;
}
__device__ __forceinline__ float bf2f(unsigned short u) {
  return __uint_as_float(((unsigned)u) << 16);
}

// ---------------- K0a: per-output-column weight scales ----------------
__global__ __launch_bounds__(256) void col_scales(const float* __restrict__ Wur,
                                                  const float* __restrict__ U,
                                                  float* __restrict__ wscWr,
                                                  float* __restrict__ wscU) {
  int j = blockIdx.x * 256 + threadIdx.x;
  if (j >= 512) return;
  float mw = 0.f, mu = 0.f;
  for (int k = 0; k < 512; k++) {
    mw = fmaxf(mw, fabsf(Wur[k * 1024 + 512 + j]));
    mu = fmaxf(mu, fabsf(U[k * 512 + j]));
  }
  wscWr[j] = fmaxf(mw, 1e-20f) * (1.0f / 127.0f);
  wscU[j]  = fmaxf(mu, 1e-20f) * (1.0f / 127.0f);
}

// ---------------- K0b: pack weights to i8, MFMA B-frag PAIR-interleaved layout ----------
// byte o = ((nt*8 + p)*64 + l)*16 + half*8 + e  <->  B[k][n],
//   k = (2p+half)*32 + ((l>>4)&3)*8 + e ; n = nt*16 + (l&15).
__global__ __launch_bounds__(256) void pack_weights_i8(const float* __restrict__ Wur,
                                                       const float* __restrict__ U,
                                                       const float* __restrict__ wscWr,
                                                       const float* __restrict__ wscU,
                                                       signed char* __restrict__ WrPK8,
                                                       signed char* __restrict__ UPK8) {
  int o = blockIdx.x * 256 + threadIdx.x;   // 0..262143
  int e = o & 7, half = (o >> 3) & 1, l = (o >> 4) & 63, p = (o >> 10) & 7, nt = o >> 13;
  int k = (2 * p + half) * 32 + ((l >> 4) & 3) * 8 + e;
  int n = nt * 16 + (l & 15);
  float i1 = __builtin_amdgcn_rcpf(wscWr[n]);
  float i2 = __builtin_amdgcn_rcpf(wscU[n]);
  int q1 = __float2int_rn(Wur[k * 1024 + 512 + n] * i1);
  int q2 = __float2int_rn(U[k * 512 + n] * i2);
  q1 = q1 > 127 ? 127 : (q1 < -127 ? -127 : q1);
  q2 = q2 > 127 ? 127 : (q2 < -127 ? -127 : q2);
  WrPK8[o] = (signed char)q1;
  UPK8[o]  = (signed char)q2;
}

// ---------------- K1: alpha = inp@Wa+ba (log domain), beta, kinc ----------------
#define ABK_ROWS 8
__global__ __launch_bounds__(64) void abk_kernel(const float* __restrict__ inp,
                                                 const float* __restrict__ Wa, const float* __restrict__ ba,
                                                 const float* __restrict__ Wb, const float* __restrict__ bb_,
                                                 const float* __restrict__ Wk, const float* __restrict__ bk,
                                                 float* __restrict__ alpha, float* __restrict__ beta,
                                                 float* __restrict__ kinc) {
  __shared__ float rows[ABK_ROWS][D];
  int tb0 = blockIdx.x * ABK_ROWS;
  for (int x = threadIdx.x; x < ABK_ROWS * D; x += 64)
    rows[x >> 9][x & 511] = inp[(size_t)tb0 * D + x];
  __syncthreads();
  int j = threadIdx.x;
  if (j >= 3 * KMIX) return;
  int wj = j % KMIX;
  int which = j / KMIX;
  const float* W = (which == 0) ? Wa : ((which == 1) ? Wb : Wk);
  const float* B = (which == 0) ? ba : ((which == 1) ? bb_ : bk);
  float acc[ABK_ROWS];
  float bias = B[wj];
#pragma unroll
  for (int r = 0; r < ABK_ROWS; r++) acc[r] = bias;
  for (int i = 0; i < D; i++) {
    float wv = W[i * KMIX + wj];
#pragma unroll
    for (int r = 0; r < ABK_ROWS; r++) acc[r] += rows[r][i] * wv;
  }
  for (int r = 0; r < ABK_ROWS; r++) {
    int tb = tb0 + r;
    float v = acc[r];
    if (which == 0) alpha[tb * KMIX + wj] = v;
    else if (which == 1) beta[tb * KMIX + wj] = expf(v);
    else kinc[tb * KMIX + wj] = expf(v);
  }
}

// ---------------- K2: k cumsum over t; writes att_k region of d_out ----------------
__global__ __launch_bounds__(256) void cumsum_kernel(const float* __restrict__ att_init,
                                                     const float* __restrict__ kinc,
                                                     float* __restrict__ kout) {
  int idx = blockIdx.x * 256 + threadIdx.x;
  if (idx >= MB * KMIX) return;
  float k = att_init[idx];
  for (int t = 0; t < TS; t++) {
    k += kinc[t * MB * KMIX + idx];
    kout[t * MB * KMIX + idx] = k;
  }
}

// ---------------- K3: phi + w GEMM; writes att_w region of d_out ----------------
#define WT 16
__global__ __launch_bounds__(512) void phi_w_kernel(const float* __restrict__ c_inp,
                                                    const float* __restrict__ alpha,
                                                    const float* __restrict__ beta,
                                                    const float* __restrict__ katt,
                                                    float* __restrict__ wout) {
  int b  = blockIdx.x / (TS / WT);
  int t0 = (blockIdx.x % (TS / WT)) * WT;
  __shared__ float phi[WT][CTS];
  __shared__ float pa[WT][KMIX], pb[WT][KMIX], pk[WT][KMIX];
  for (int x = threadIdx.x; x < WT * KMIX; x += 512) {
    int tt = x / KMIX, j = x % KMIX;
    int tb = (t0 + tt) * MB + b;
    pa[tt][j] = alpha[tb * KMIX + j];
    pb[tt][j] = beta[tb * KMIX + j];
    pk[tt][j] = katt[tb * KMIX + j];
  }
  __syncthreads();
  {
    int c = threadIdx.x;
    float fc = (float)c;
#pragma unroll
    for (int tt = 0; tt < WT; tt++) {
      float s = 0.f;
#pragma unroll
      for (int j = 0; j < KMIX; j++) {
        float dd = pk[tt][j] - fc;
        s += expf(pa[tt][j] - pb[tt][j] * dd * dd);
      }
      phi[tt][c] = s;
    }
  }
  __syncthreads();
  {
    int d = threadIdx.x;
    float acc[WT];
#pragma unroll
    for (int tt = 0; tt < WT; tt++) acc[tt] = 0.f;
    const float* cb = c_inp + (size_t)b * D + d;
    for (int c2 = 0; c2 < CTS; c2++) {
      float cv = cb[(size_t)c2 * (MB * D)];
#pragma unroll
      for (int tt = 0; tt < WT; tt++) acc[tt] += phi[tt][c2] * cv;
    }
    for (int tt = 0; tt < WT; tt++)
      wout[((size_t)(t0 + tt) * MB + b) * D + d] = acc[tt];
  }
}

// ---------------- K4/K5: fp32 tiled GEMM, 128x128 tile ----------------
__global__ __launch_bounds__(256) void gemm128(const float* __restrict__ A,
                                               const float* __restrict__ B,
                                               const float* __restrict__ bias,
                                               const float* __restrict__ wadd,
                                               float* __restrict__ C,
                                               int Kdim, int ldb, int Nout, int remapHalf) {
  __shared__ float As[8][128];
  __shared__ float Bs[8][128];
  const int bm = blockIdx.x, bn = blockIdx.y;
  const int tid = threadIdx.x;
  const int tm = (tid >> 4) << 3;
  const int tn = (tid & 15) << 3;
  const int colOff = (remapHalf && bn >= 4) ? 512 : 0;
  const int n0 = bn * 128;
  float acc[8][8];
#pragma unroll
  for (int i = 0; i < 8; i++)
#pragma unroll
    for (int j = 0; j < 8; j++) acc[i][j] = 0.f;
  const int ar = tid >> 1;
  const int ak = (tid & 1) << 2;
  const int bkr = tid >> 5;
  const int bc = (tid & 31) << 2;
  const float* Aptr = A + (size_t)(bm * 128 + ar) * Kdim + ak;
  const float* Bptr = B + (size_t)bkr * ldb + n0 + colOff + bc;
  for (int k0 = 0; k0 < Kdim; k0 += 8) {
    float4 a4 = *(const float4*)(Aptr + k0);
    float4 b4 = *(const float4*)(Bptr + (size_t)k0 * ldb);
    As[ak + 0][ar] = a4.x; As[ak + 1][ar] = a4.y; As[ak + 2][ar] = a4.z; As[ak + 3][ar] = a4.w;
    *(float4*)&Bs[bkr][bc] = b4;
    __syncthreads();
#pragma unroll
    for (int kk = 0; kk < 8; kk++) {
      float a8[8], b8[8];
      *(float4*)&a8[0] = *(const float4*)&As[kk][tm];
      *(float4*)&a8[4] = *(const float4*)&As[kk][tm + 4];
      *(float4*)&b8[0] = *(const float4*)&Bs[kk][tn];
      *(float4*)&b8[4] = *(const float4*)&Bs[kk][tn + 4];
#pragma unroll
      for (int i = 0; i < 8; i++)
#pragma unroll
        for (int j = 0; j < 8; j++) acc[i][j] += a8[i] * b8[j];
    }
    __syncthreads();
  }
  float bb8[8];
#pragma unroll
  for (int j = 0; j < 8; j++) bb8[j] = bias[n0 + colOff + tn + j];
#pragma unroll
  for (int i = 0; i < 8; i++) {
    int m = bm * 128 + tm + i;
    size_t co = (size_t)m * Nout + n0 + tn;
    float v[8];
#pragma unroll
    for (int j = 0; j < 8; j++) v[j] = acc[i][j] + bb8[j];
    if (wadd) {
      float4 w0 = *(const float4*)&wadd[co];
      float4 w1 = *(const float4*)&wadd[co + 4];
      v[0] += w0.x; v[1] += w0.y; v[2] += w0.z; v[3] += w0.w;
      v[4] += w1.x; v[5] += w1.y; v[6] += w1.z; v[7] += w1.w;
    }
    *(float4*)&C[co]     = make_float4(v[0], v[1], v[2], v[3]);
    *(float4*)&C[co + 4] = make_float4(v[4], v[5], v[6], v[7]);
  }
}

// ---------------- K5b: transpose+pack F2 -> F2T bf16 [t][j<512][m][2(s,g)] ----------------
// grid = 256 t x 8 jb ; 256 thr. s = F2[(t*64+m)*1024 + j], g = F2[... + 512 + j].
__global__ __launch_bounds__(256) void pack_f2t(const float* __restrict__ F2,
                                                unsigned short* __restrict__ F2T) {
  __shared__ float ts_[64][65], tg_[64][65];
  int t = blockIdx.x >> 3, jb = (blockIdx.x & 7) << 6;
  const float* src = F2 + (size_t)t * 64 * 1024;
  for (int mm = 0; mm < 64; mm += 4) {
    int m = mm + (threadIdx.x >> 6);
    int c = threadIdx.x & 63;
    ts_[m][c] = src[(size_t)m * 1024 + jb + c];
    tg_[m][c] = src[(size_t)m * 1024 + 512 + jb + c];
  }
  __syncthreads();
  unsigned short* dst = F2T + ((size_t)t * 512 + jb) * 128;
  for (int base = threadIdx.x; base < 64 * 128; base += 256) {
    int j = base >> 7, idx = base & 127, m = idx >> 1, sel = idx & 1;
    float v = sel ? tg_[m][j] : ts_[m][j];
    dst[(size_t)j * 128 + idx] = f2bf(v);
  }
}

// ---------------- K6: i8 MFMA recurrence, 1024 threads (16 waves, 4/SIMD) ----------------
// 4 blocks x 1024 thr, 16 batches/block, wave owns 2 n-tiles. Weights streamed from L2
// each step (512 KB i8, dwordx4 pair-loads, plain inline loads — compiler-scheduled).
// F2 read via F2T bf16 packed layout: 2 x 16B loads/thread/step (was 32 x 4B).
// A-buffer (LDS, 8KB each): byte (page, l, half, e) = A[m=l&15][k=(2*page+half)*32+((l>>4)&3)*8+e].

__device__ __forceinline__ int a8off(int m, int j) {
  return ((j >> 6) << 10) + (((((j >> 3) & 3) << 4) + m) << 4) + (((j >> 5) & 1) << 3) + (j & 7);
}

__device__ __forceinline__ float fast_sigmoid(float x) {
  return __builtin_amdgcn_rcpf(1.f + __expf(-x));
}
__device__ __forceinline__ float fast_tanh(float x) {
  x = fminf(15.f, fmaxf(-15.f, x));
  float e = __expf(2.f * x);
  return 1.f - 2.f * __builtin_amdgcn_rcpf(e + 1.f);
}

__global__ __launch_bounds__(1024) void recurrence_i8(
    const unsigned short* __restrict__ F2T,
    const signed char* __restrict__ WrPK8,
    const signed char* __restrict__ UPK8,
    const float* __restrict__ wscWr,
    const float* __restrict__ wscU,
    const float* __restrict__ gru_init,
    float* __restrict__ hout) {
  __shared__ long long hq8[1024];    // 8KB i8 A-buffer (h)
  __shared__ long long srq8[1024];   // 8KB i8 A-buffer (sr)
  signed char* hqc  = (signed char*)hq8;
  signed char* srqc = (signed char*)srq8;
  const int tid  = threadIdx.x;
  const int wave = tid >> 6;        // 0..15
  const int lane = tid & 63;
  const int lg = lane >> 4;
  const int ln = lane & 15;
  const int b0 = blockIdx.x * 16;

  // per-wave B base pointers (pair-interleaved layout), lane folded in
  const signed char* wrq0 = WrPK8 + (size_t)(wave * 2 + 0) * 8192 + lane * 16;
  const signed char* wrq1 = WrPK8 + (size_t)(wave * 2 + 1) * 8192 + lane * 16;
  const signed char* uq0  = UPK8  + (size_t)(wave * 2 + 0) * 8192 + lane * 16;
  const signed char* uq1  = UPK8  + (size_t)(wave * 2 + 1) * 8192 + lane * 16;

  // per-thread output-column dequant scales (j_q = (wave*2+q)*16 + ln)
  float wscWrR[2], wscUR[2];
#pragma unroll
  for (int q = 0; q < 2; q++) {
    int j = ((wave * 2 + q) << 4) + ln;
    wscWrR[q] = wscWr[j];
    wscUR[q]  = wscU[j];
  }

  // ---- init h: fp32 master in regs, i8 copy in LDS ----
  float hreg[2][4];
  float hdq = 2.0f / 127.0f;
  {
    float hqi = 127.0f / 2.0f;
#pragma unroll
    for (int q = 0; q < 2; q++) {
      int j = ((wave * 2 + q) << 4) + ln;
#pragma unroll
      for (int r = 0; r < 4; r++) {
        int m = (lg << 2) + r;
        float v = gru_init[(b0 + m) * D + j];
        hreg[q][r] = v;
        int qv = __float2int_rn(v * hqi);
        qv = qv > 127 ? 127 : (qv < -127 ? -127 : qv);
        hqc[a8off(m, j)] = (signed char)qv;
      }
    }
  }
  __syncthreads();

  const i32x4 z4 = {0, 0, 0, 0};
#pragma unroll 1
  for (int t = 0; t < TS; t++) {
    // s/g loads: 2 x 16B from F2T (bf16 packed [j][m][2]); consumed after matvec1
    const unsigned short* f2t = F2T + (size_t)t * (512 * 128) + (size_t)b0 * 0;  // b0 folded below
    float sreg[2][4], greg[2][4];
#pragma unroll
    for (int q = 0; q < 2; q++) {
      int j = ((wave * 2 + q) << 4) + ln;
      ushort8 v = *(const ushort8*)(f2t + (size_t)j * 128 + ((b0 + (lg << 2)) << 1));
#pragma unroll
      for (int r = 0; r < 4; r++) {
        sreg[q][r] = bf2f(v[2 * r]);
        greg[q][r] = bf2f(v[2 * r + 1]);
      }
    }
    // ---- matvec1: c1 = h @ Wr (i8, K=32, frag-pairs) ----
    i32x4 c1[2] = {z4, z4};
#pragma unroll
    for (int p = 0; p < 8; p++) {
      ll2 a2 = *(const ll2*)(hqc + (p << 10) + (lane << 4));
      ll2 w0 = *(const ll2*)(wrq0 + (p << 10));
      ll2 w1 = *(const ll2*)(wrq1 + (p << 10));
      c1[0] = __builtin_amdgcn_mfma_i32_16x16x32_i8(a2[0], w0[0], c1[0], 0, 0, 0);
      c1[0] = __builtin_amdgcn_mfma_i32_16x16x32_i8(a2[1], w0[1], c1[0], 0, 0, 0);
      c1[1] = __builtin_amdgcn_mfma_i32_16x16x32_i8(a2[0], w1[0], c1[1], 0, 0, 0);
      c1[1] = __builtin_amdgcn_mfma_i32_16x16x32_i8(a2[1], w1[1], c1[1], 0, 0, 0);
    }
    // ---- epilogue 1: sr = s * sigmoid(dequant(c1) + g), quantize to i8 (+-8 range) ----
#pragma unroll
    for (int q = 0; q < 2; q++) {
      int j = ((wave * 2 + q) << 4) + ln;
      float d1 = hdq * wscWrR[q];
#pragma unroll
      for (int r = 0; r < 4; r++) {
        int m = (lg << 2) + r;
        float c1f = (float)c1[q][r] * d1;
        float rr = fast_sigmoid(c1f + greg[q][r]);
        float sr = sreg[q][r] * rr;
        int qv = __float2int_rn(sr * (127.0f / 8.0f));
        qv = qv > 127 ? 127 : (qv < -127 ? -127 : qv);
        srqc[a8off(m, j)] = (signed char)qv;
      }
    }
    __syncthreads();
    // ---- matvec2: c2 = sr @ U ----
    i32x4 c2[2] = {z4, z4};
#pragma unroll
    for (int p = 0; p < 8; p++) {
      ll2 a2 = *(const ll2*)(srqc + (p << 10) + (lane << 4));
      ll2 w0 = *(const ll2*)(uq0 + (p << 10));
      ll2 w1 = *(const ll2*)(uq1 + (p << 10));
      c2[0] = __builtin_amdgcn_mfma_i32_16x16x32_i8(a2[0], w0[0], c2[0], 0, 0, 0);
      c2[0] = __builtin_amdgcn_mfma_i32_16x16x32_i8(a2[1], w0[1], c2[0], 0, 0, 0);
      c2[1] = __builtin_amdgcn_mfma_i32_16x16x32_i8(a2[0], w1[0], c2[1], 0, 0, 0);
      c2[1] = __builtin_amdgcn_mfma_i32_16x16x32_i8(a2[1], w1[1], c2[1], 0, 0, 0);
    }
    // ---- epilogue 2: h += 1 + tanh(dequant(c2) + s); write hout + quantized h ----
    {
      float hbn = 2.0f * (float)(t + 1) + 2.0f;
      float hqin = 127.0f / hbn;
#pragma unroll
      for (int q = 0; q < 2; q++) {
        int j = ((wave * 2 + q) << 4) + ln;
        float d2 = (8.0f / 127.0f) * wscUR[q];
#pragma unroll
        for (int r = 0; r < 4; r++) {
          int m = (lg << 2) + r;
          float c2f = (float)c2[q][r] * d2;
          float hn = hreg[q][r] + 1.f + fast_tanh(c2f + sreg[q][r]);
          hreg[q][r] = hn;
          hout[((size_t)t * MB + (b0 + m)) * D + j] = hn;
          int qv = __float2int_rn(hn * hqin);
          qv = qv > 127 ? 127 : (qv < -127 ? -127 : qv);
          hqc[a8off(m, j)] = (signed char)qv;
        }
      }
      hdq = hbn * (1.0f / 127.0f);
    }
    __syncthreads();
  }
}

extern "C" void kernel_launch(void* const* d_in, const int* in_sizes, int n_in,
                              void* d_out, int out_size, void* d_ws, size_t ws_size,
                              hipStream_t stream) {
  const float* c_inp    = (const float*)d_in[0];
  const float* inp      = (const float*)d_in[1];
  const float* gru_init = (const float*)d_in[2];
  const float* att_init = (const float*)d_in[3];
  const float* Wa   = (const float*)d_in[4];
  const float* ba   = (const float*)d_in[5];
  const float* Wb   = (const float*)d_in[6];
  const float* bb   = (const float*)d_in[7];
  const float* Wk   = (const float*)d_in[8];
  const float* bk   = (const float*)d_in[9];
  const float* Wif  = (const float*)d_in[10];
  const float* bif  = (const float*)d_in[11];
  const float* Wfork= (const float*)d_in[12];
  const float* bfork= (const float*)d_in[13];
  const float* Wur  = (const float*)d_in[14];
  const float* U    = (const float*)d_in[15];

  float* out = (float*)d_out;
  float* hid  = out;
  float* attk = out + ATTK_OFF;
  float* attw = out + ATTW_OFF;

  char* ws = (char*)d_ws;
  signed char* WrPK8 = (signed char*)(ws + WS_WRPK8);
  signed char* UPK8  = (signed char*)(ws + WS_UPK8);
  float* wscWr = (float*)(ws + WS_WSC);
  float* wscU  = (float*)(ws + WS_WSC + 2048);
  float* alpha = (float*)(ws + WS_ALPHA);
  float* beta  = (float*)(ws + WS_BETA);
  float* kinc  = (float*)(ws + WS_KINC);
  float* X     = (float*)(ws + WS_X);
  unsigned short* F2T = (unsigned short*)(ws + WS_X);   // reuses X after gemm#2
  float* F2    = (float*)(ws + WS_F2);

  hipLaunchKernelGGL(col_scales, dim3(2), dim3(256), 0, stream, Wur, U, wscWr, wscU);
  hipLaunchKernelGGL(pack_weights_i8, dim3(1024), dim3(256), 0, stream,
                     Wur, U, wscWr, wscU, WrPK8, UPK8);
  hipLaunchKernelGGL(abk_kernel, dim3(TS * MB / ABK_ROWS), dim3(64), 0, stream,
                     inp, Wa, ba, Wb, bb, Wk, bk, alpha, beta, kinc);
  hipLaunchKernelGGL(cumsum_kernel, dim3((MB * KMIX + 255) / 256), dim3(256), 0, stream,
                     att_init, kinc, attk);
  hipLaunchKernelGGL(phi_w_kernel, dim3(MB * (TS / WT)), dim3(512), 0, stream,
                     c_inp, alpha, beta, attk, attw);
  hipLaunchKernelGGL(gemm128, dim3(TS * MB / 128, D / 128), dim3(256), 0, stream,
                     inp, Wif, bif, attw, X, D, D, D, 0);
  hipLaunchKernelGGL(gemm128, dim3(TS * MB / 128, 1024 / 128), dim3(256), 0, stream,
                     X, Wfork, bfork, (const float*)nullptr, F2, D, 3 * D, 1024, 1);
  hipLaunchKernelGGL(pack_f2t, dim3(256 * 8), dim3(256), 0, stream, F2, F2T);
  hipLaunchKernelGGL(recurrence_i8, dim3(4), dim3(1024), 0, stream,
                     F2T, WrPK8, UPK8, wscWr, wscU, gru_init, hid);
}